// Round 5
// baseline (336.918 us; speedup 1.0000x reference)
//
#include <hip/hip_runtime.h>
#include <hip/hip_bf16.h>
#include <stdint.h>

// ReadoutLayer: Wx = x @ W^T (+b cancels under BN), BatchNorm(train) over B*T,
// then ut = a*ut + (1-a)*wxn per t with acc += softmax(ut, axis=H).
// R5: gemm with fragment-ordered LDS (conflict-free ds_read_b128 AND conflict-free
// global_load_lds: chunk = 64 lanes x 16B sequential) + true double-buffer (DMA for
// slab s+1 issued top-of-iter, drained by end-of-iter barrier -> overlapped by MFMA).
// Tail vectorized: 8h/thread agg (uint4), 4h/thread softmax (uint2), wide grids.

namespace {
constexpr int kB = 32;
constexpr int kT = 2000;
constexpr int kD = 512;
constexpr int kH = 512;
constexpr int kM = kB * kT;   // 64000 rows
constexpr int kL = 20;        // chunk length
constexpr int kC = kT / kL;   // 100 chunks per batch
constexpr float kALo = 0.81873075307798182f;  // exp(-1/5)
constexpr float kAHi = 0.96078943915232320f;  // exp(-1/25)

typedef __bf16 bf16x8 __attribute__((ext_vector_type(8)));
typedef float floatx16 __attribute__((ext_vector_type(16)));

__device__ __forceinline__ float bf2f(unsigned short u) {
  return __builtin_bit_cast(float, (unsigned)u << 16);
}
__device__ __forceinline__ float clipa(float a) {
  return fminf(fmaxf(a, kALo), kAHi);
}
__device__ __forceinline__ float pow20(float a) {
  const float a2 = a * a, a4 = a2 * a2, a5 = a4 * a;
  const float a10 = a5 * a5;
  return a10 * a10;
}
// async global->LDS, 16B/lane; HW dest = wave-uniform base + lane*16
__device__ __forceinline__ void gld_lds16(const void* g, void* l) {
  __builtin_amdgcn_global_load_lds(
      (const __attribute__((address_space(1))) uint32_t*)g,
      (__attribute__((address_space(3))) uint32_t*)(uintptr_t)l, 16, 0, 0);
}

// ---------- K0: W f32 -> bf16 ----------
__global__ __launch_bounds__(256) void wcvt_k(const float* __restrict__ W,
                                              __bf16* __restrict__ Wbf) {
  const int t = blockIdx.x * 256 + threadIdx.x;
  const float4 a0 = ((const float4*)W)[t * 2];
  const float4 a1 = ((const float4*)W)[t * 2 + 1];
  bf16x8 v;
  v[0] = (__bf16)a0.x; v[1] = (__bf16)a0.y; v[2] = (__bf16)a0.z; v[3] = (__bf16)a0.w;
  v[4] = (__bf16)a1.x; v[5] = (__bf16)a1.y; v[6] = (__bf16)a1.z; v[7] = (__bf16)a1.w;
  *(bf16x8*)(Wbf + (size_t)t * 8) = v;
}

// ---------- K1: GEMM 64 rows x 512 cols per block, dbuf, fragment-ordered LDS ----------
// 8 waves; wave w: row-tile rt=w>>2 (32 rows), col-tiles ct0=(w&3)*4 .. +4.
// LDS chunk = 1KB = one MFMA operand fragment for a whole wave (lane L -> L*16).
// A-chunk (rt,kh) lane L: A[rt*32+(L&31)][kh*16+(L>>5)*8 ..+8]. B same with n=ct*32+(L&31).
__global__ __launch_bounds__(512, 2) void gemm_k(const float* __restrict__ X,
                                                 const __bf16* __restrict__ Wbf,
                                                 unsigned short* __restrict__ Wxb,
                                                 float* __restrict__ partial) {
  __shared__ __align__(16) char AsB[2][4 * 1024];   // 4 chunks: (rt*2+kh)
  __shared__ __align__(16) char BsB[2][32 * 1024];  // 32 chunks: (ct*2+kh)
  __shared__ float sred[2][kH];
  const int tid = threadIdx.x;
  const size_t row0 = (size_t)blockIdx.x * 64;
  const int w = tid >> 6, L = tid & 63;
  const int rt = w >> 2, ct0 = (w & 3) * 4;
  const int lhalf = L >> 5, l32 = L & 31;
  // A staging: threads 0..255: m=t>>2, kq=t&3 (8 consecutive k)
  const int am = tid >> 2, akq = tid & 3;
  const int a_off = ((am >> 5) * 2 + (akq >> 1)) * 1024 + ((akq & 1) * 32 + (am & 31)) * 16;
  const float* xptr = X + (row0 + am) * kD + akq * 8;

  floatx16 acc[4] = {};
  float4 ap0, ap1;

  auto loadA = [&](int s) {
    if (tid < 256) {
      const float4* p = (const float4*)(xptr + s * 32);
      ap0 = p[0]; ap1 = p[1];
    }
  };
  auto storeA = [&](int buf) {
    if (tid < 256) {
      bf16x8 v;
      v[0] = (__bf16)ap0.x; v[1] = (__bf16)ap0.y; v[2] = (__bf16)ap0.z; v[3] = (__bf16)ap0.w;
      v[4] = (__bf16)ap1.x; v[5] = (__bf16)ap1.y; v[6] = (__bf16)ap1.z; v[7] = (__bf16)ap1.w;
      *(bf16x8*)(AsB[buf] + a_off) = v;
    }
  };
  auto dmaB = [&](int s, int buf) {
#pragma unroll
    for (int j = 0; j < 4; ++j) {
      const int q = w * 4 + j;              // chunk id: ct=q>>1, kh=q&1
      const int n = (q >> 1) * 32 + l32;
      const int k = s * 32 + (q & 1) * 16 + lhalf * 8;
      gld_lds16(Wbf + (size_t)n * kD + k, BsB[buf] + q * 1024);
    }
  };

  loadA(0);
  dmaB(0, 0);
  storeA(0);
  __syncthreads();  // prologue drain (once)

#pragma unroll 1
  for (int s = 0; s < 16; ++s) {
    const int cur = s & 1, nxt = cur ^ 1;
    if (s < 15) {
      dmaB(s + 1, nxt);   // issued BEFORE MFMA phase; drained by end barrier -> overlapped
      loadA(s + 1);
    }
#pragma unroll
    for (int kh = 0; kh < 2; ++kh) {
      const bf16x8 af = *(const bf16x8*)(AsB[cur] + (rt * 2 + kh) * 1024 + L * 16);
#pragma unroll
      for (int c = 0; c < 4; ++c) {
        const bf16x8 bfr =
            *(const bf16x8*)(BsB[cur] + ((ct0 + c) * 2 + kh) * 1024 + L * 16);
        acc[c] = __builtin_amdgcn_mfma_f32_32x32x16_bf16(af, bfr, acc[c], 0, 0, 0);
      }
    }
    if (s < 15) storeA(nxt);  // other buffer: no hazard with this iter's reads
    __syncthreads();
  }

  // ---- epilogue 1: column sums/sumsq (LDS atomics only) ----
  sred[0][tid] = 0.f;
  sred[1][tid] = 0.f;
  __syncthreads();
#pragma unroll
  for (int c = 0; c < 4; ++c) {
    float s = 0.f, q = 0.f;
#pragma unroll
    for (int r = 0; r < 16; ++r) {
      const float v = acc[c][r];
      s += v;
      q += v * v;
    }
    s += __shfl_xor(s, 32);
    q += __shfl_xor(q, 32);
    if (lhalf == 0) {
      atomicAdd(&sred[0][(ct0 + c) * 32 + l32], s);
      atomicAdd(&sred[1][(ct0 + c) * 32 + l32], q);
    }
  }
  // ---- epilogue 2: store Wx bf16, packed dword pairs via shfl ----
  // C/D layout (32x32): col = lane&31, row = 4*(lane>>5) + (reg&3) + 8*(reg>>2)
#pragma unroll
  for (int c = 0; c < 4; ++c) {
    const int col = (ct0 + c) * 32 + l32;
#pragma unroll
    for (int r = 0; r < 16; ++r) {
      const int row = rt * 32 + 4 * lhalf + (r & 3) + 8 * (r >> 2);
      const unsigned short u = __builtin_bit_cast(unsigned short, (__bf16)acc[c][r]);
      const unsigned un = __shfl_down((unsigned)u, 1);
      if ((l32 & 1) == 0)
        *(unsigned*)(Wxb + (row0 + row) * (size_t)kH + col) = (unsigned)u | (un << 16);
    }
  }
  __syncthreads();
  partial[(size_t)blockIdx.x * 1024 + tid] = sred[0][tid];
  partial[(size_t)blockIdx.x * 1024 + 512 + tid] = sred[1][tid];
}

// ---------- K2: reduce per-block partials 1000 -> 40 (no atomics) ----------
__global__ __launch_bounds__(512) void red1_k(const float* __restrict__ partial,
                                              float* __restrict__ partial2) {
  const int tid = threadIdx.x;
  const int r0 = blockIdx.x * 25;
  float s0 = 0.f, s1 = 0.f;
#pragma unroll 5
  for (int r = 0; r < 25; ++r) {
    s0 += partial[(size_t)(r0 + r) * 1024 + tid];
    s1 += partial[(size_t)(r0 + r) * 1024 + 512 + tid];
  }
  partial2[(size_t)blockIdx.x * 1024 + tid] = s0;
  partial2[(size_t)blockIdx.x * 1024 + 512 + tid] = s1;
}

// ---------- K3: finalize BN scale/shift + alpha params ----------
// prm: [0]=scale [512]=shift [1024]=a [1536]=1-a [2048]=a^L
__global__ __launch_bounds__(512) void finalize_k(const float* __restrict__ partial2,
                                                  const float* __restrict__ alpha,
                                                  const float* __restrict__ gamma,
                                                  const float* __restrict__ beta,
                                                  float* __restrict__ prm) {
  const int h = threadIdx.x;
  float s0 = 0.f, s1 = 0.f;
#pragma unroll 8
  for (int r = 0; r < 40; ++r) {
    s0 += partial2[(size_t)r * 1024 + h];
    s1 += partial2[(size_t)r * 1024 + 512 + h];
  }
  const float inv_n = 1.0f / (float)kM;
  const float mean = s0 * inv_n;
  const float var = s1 * inv_n - mean * mean;
  const float sc = gamma[h] * rsqrtf(var + 1e-5f);
  const float sh = beta[h] - mean * sc;
  const float a = clipa(alpha[h]);
  prm[h] = sc;
  prm[kH + h] = sh;
  prm[2 * kH + h] = a;
  prm[3 * kH + h] = 1.0f - a;
  prm[4 * kH + h] = pow20(a);
}

// ---------- K4: per-chunk RAW EWMA, 8 h per lane (uint4 loads) ----------
// grid 800 = (b, cgroup of 4); 4 waves, wave wv -> chunk cg*4+wv.
__global__ __launch_bounds__(256) void agg_k(const unsigned short* __restrict__ Wxb,
                                             const float* __restrict__ alpha,
                                             float* __restrict__ vbuf) {
  const int g = blockIdx.x;
  const int b = g / (kC / 4), cg = g % (kC / 4);
  const int wv = threadIdx.x >> 6, lane = threadIdx.x & 63;
  const int c = cg * 4 + wv;
  const int h0 = lane * 8;
  float a[8], v[8];
  const float4 av0 = *(const float4*)(alpha + h0);
  const float4 av1 = *(const float4*)(alpha + h0 + 4);
  a[0] = av0.x; a[1] = av0.y; a[2] = av0.z; a[3] = av0.w;
  a[4] = av1.x; a[5] = av1.y; a[6] = av1.z; a[7] = av1.w;
#pragma unroll
  for (int j = 0; j < 8; ++j) { a[j] = clipa(a[j]); v[j] = 0.f; }
  const unsigned short* base = Wxb + ((size_t)b * kT + (size_t)c * kL) * kH + h0;
#pragma unroll
  for (int i = 0; i < kL; ++i) {
    const uint4 p = *(const uint4*)(base + (size_t)i * kH);
    const unsigned pw[4] = {p.x, p.y, p.z, p.w};
#pragma unroll
    for (int d = 0; d < 4; ++d) {
      const float w0 = bf2f((unsigned short)(pw[d] & 0xffff));
      const float w1 = bf2f((unsigned short)(pw[d] >> 16));
      v[2 * d] = a[2 * d] * v[2 * d] + (1.f - a[2 * d]) * w0;
      v[2 * d + 1] = a[2 * d + 1] * v[2 * d + 1] + (1.f - a[2 * d + 1]) * w1;
    }
  }
  float* dst = vbuf + ((size_t)b * kC + c) * kH + h0;
  *(float4*)dst = make_float4(v[0], v[1], v[2], v[3]);
  *(float4*)(dst + 4) = make_float4(v[4], v[5], v[6], v[7]);
}

// ---------- K5: chunk-boundary scan, BN folded: u' = a^20 u + sc*v + sh*(1-a^20) ----------
__global__ __launch_bounds__(512) void scan_k(const float* __restrict__ ut0,
                                              const float* __restrict__ alpha,
                                              const float* __restrict__ prm,
                                              float* __restrict__ vbuf) {
  const int b = blockIdx.x;
  const int h = threadIdx.x;
  const float a20 = pow20(clipa(alpha[h]));
  const float sc = prm[h];
  const float shc = prm[kH + h] * (1.0f - a20);
  float u = ut0[(size_t)b * kH + h];
  float vc[10];
#pragma unroll 1
  for (int cb = 0; cb < kC; cb += 10) {
#pragma unroll
    for (int j = 0; j < 10; ++j)
      vc[j] = vbuf[((size_t)b * kC + cb + j) * kH + h];  // independent, pipelined
#pragma unroll
    for (int j = 0; j < 10; ++j) {
      vbuf[((size_t)b * kC + cb + j) * kH + h] = u;      // ustart for chunk
      u = a20 * u + sc * vc[j] + shc;
    }
  }
}

// ---------- K6: per-chunk softmax accumulation, 4 h per thread ----------
__global__ __launch_bounds__(128) void soft_k(const unsigned short* __restrict__ Wxb,
                                              const float* __restrict__ prm,
                                              const float* __restrict__ ustart,
                                              float* __restrict__ accp) {
  __shared__ float part[kL][2];
  __shared__ float zinv[kL];
  const int bc = blockIdx.x;
  const int b = bc / kC, c = bc % kC;
  const int t = threadIdx.x;
  const int wv = t >> 6, lane = t & 63;
  const int h0 = t * 4;
  const float4 sc = *(const float4*)(prm + h0);
  const float4 sh = *(const float4*)(prm + kH + h0);
  const float4 aa = *(const float4*)(prm + 2 * kH + h0);
  const float4 om = *(const float4*)(prm + 3 * kH + h0);
  float4 u = *(const float4*)(ustart + (size_t)bc * kH + h0);
  const unsigned short* base = Wxb + ((size_t)b * kT + (size_t)c * kL) * kH + h0;
  float e[kL][4];
#pragma unroll
  for (int i = 0; i < kL; ++i) {
    const uint2 p = *(const uint2*)(base + (size_t)i * kH);
    const float w0 = bf2f((unsigned short)(p.x & 0xffff)) * sc.x + sh.x;
    const float w1 = bf2f((unsigned short)(p.x >> 16)) * sc.y + sh.y;
    const float w2 = bf2f((unsigned short)(p.y & 0xffff)) * sc.z + sh.z;
    const float w3 = bf2f((unsigned short)(p.y >> 16)) * sc.w + sh.w;
    u.x = aa.x * u.x + om.x * w0;
    u.y = aa.y * u.y + om.y * w1;
    u.z = aa.z * u.z + om.z * w2;
    u.w = aa.w * u.w + om.w * w3;
    e[i][0] = __expf(u.x); e[i][1] = __expf(u.y);
    e[i][2] = __expf(u.z); e[i][3] = __expf(u.w);
    float s = (e[i][0] + e[i][1]) + (e[i][2] + e[i][3]);
#pragma unroll
    for (int off = 32; off > 0; off >>= 1) s += __shfl_xor(s, off);
    if (lane == 0) part[i][wv] = s;
  }
  __syncthreads();
  if (t < kL) zinv[t] = 1.0f / (part[t][0] + part[t][1]);
  __syncthreads();
  float4 o = make_float4(0.f, 0.f, 0.f, 0.f);
#pragma unroll
  for (int i = 0; i < kL; ++i) {
    const float z = zinv[i];
    o.x += e[i][0] * z; o.y += e[i][1] * z;
    o.z += e[i][2] * z; o.w += e[i][3] * z;
  }
  *(float4*)(accp + (size_t)bc * kH + h0) = o;
}

// ---------- K7: reduce chunk partials -> out (128 blocks) ----------
__global__ __launch_bounds__(128) void out_red_k(const float* __restrict__ accp,
                                                 float* __restrict__ out) {
  const int b = blockIdx.x >> 2, q = blockIdx.x & 3;
  const int h = q * 128 + threadIdx.x;
  float s = 0.f;
#pragma unroll 5
  for (int c = 0; c < kC; ++c) s += accp[((size_t)b * kC + c) * kH + h];
  out[(size_t)b * kH + h] = s;
}

}  // namespace

extern "C" void kernel_launch(void* const* d_in, const int* in_sizes, int n_in,
                              void* d_out, int out_size, void* d_ws, size_t ws_size,
                              hipStream_t stream) {
  const float* x = (const float*)d_in[0];      // [32,2000,512]
  const float* Wm = (const float*)d_in[1];     // [512,512]
  // d_in[2] = b: unused — BN mean subtraction cancels the bias exactly
  const float* alpha = (const float*)d_in[3];
  const float* gamma = (const float*)d_in[4];
  const float* beta = (const float*)d_in[5];
  const float* ut0 = (const float*)d_in[6];
  float* out = (float*)d_out;                  // [32,1,512]

  float* wsp = (float*)d_ws;
  float* vbuf = wsp;                                   // 3200*512 f
  float* accp = vbuf + (size_t)kB * kC * kH;           // 3200*512 f
  float* partial = accp + (size_t)kB * kC * kH;        // 1000*1024 f
  float* partial2 = partial + (size_t)1000 * 1024;     // 40*1024 f
  float* prm = partial2 + (size_t)40 * 1024;           // 2560 f
  __bf16* Wbf = (__bf16*)(prm + 5 * kH);               // 262144 bf16 (16B-aligned)
  unsigned short* Wxb = (unsigned short*)(Wbf + (size_t)kH * kD);  // 65.5 MB

  wcvt_k<<<128, 256, 0, stream>>>(Wm, Wbf);
  gemm_k<<<kM / 64, 512, 0, stream>>>(x, Wbf, Wxb, partial);
  red1_k<<<40, 512, 0, stream>>>(partial, partial2);
  agg_k<<<kB * (kC / 4), 256, 0, stream>>>(Wxb, alpha, vbuf);  // L3-hot Wxb
  finalize_k<<<1, 512, 0, stream>>>(partial2, alpha, gamma, beta, prm);
  scan_k<<<kB, 512, 0, stream>>>(ut0, alpha, prm, vbuf);
  soft_k<<<kB * kC, 128, 0, stream>>>(Wxb, prm, vbuf, accp);
  out_red_k<<<kB * 4, 128, 0, stream>>>(accp, out);
}